// Round 1
// baseline (1834.440 us; speedup 1.0000x reference)
//
#include <hip/hip_runtime.h>
#include <hip/hip_bf16.h>

// Problem constants
#define BB 2
#define LL 5000
#define CIN 256
#define CLOI 128
#define HH 256
#define WW 256
#define HWP (HH*WW)        // 65536
#define NPTS0 32
#define NPTS1 8
#define PLANES 64
#define EPSV 1e-5f

// workspace layout
#define X_BYTES ((size_t)BB * HWP * CLOI * 2)          // bf16 fc1 map, channel-last: 33,554,432 B
// xs: [10000][8][128] f32 (t-major then c): 40,960,000 B

typedef unsigned int uint;
typedef unsigned short ushort;

__device__ __forceinline__ float bf2f(ushort u) {
    uint v = ((uint)u) << 16;
    return __uint_as_float(v);
}
__device__ __forceinline__ ushort f2bf(float f) {
    uint x = __float_as_uint(f);
    uint r = (x + 0x7fffu + ((x >> 16) & 1u)) >> 16;   // RNE
    return (ushort)r;
}
__device__ __forceinline__ uint pack2(float a, float b) {
    return (uint)f2bf(a) | ((uint)f2bf(b) << 16);
}

// ---------------------------------------------------------------------------
// Kernel A: fc1 1x1 conv as GEMM. x[b][p][o] (channel-last, bf16) = W[o][c]*F[b][c][p]+bias
// Tile: 128 outputs x 64 pixels per block. 256 threads: tx=pixel group(16), ty=o group(16).
// ---------------------------------------------------------------------------
__global__ __launch_bounds__(256) void fc1_kernel(
    const float* __restrict__ feature, const float* __restrict__ fc1_w,
    const float* __restrict__ fc1_b, ushort* __restrict__ xout)
{
    __shared__ float sW[16 * 132];   // [kk][o] padded 132 (16B aligned rows)
    __shared__ float sF[16 * 64];    // [kk][pp]

    int tid = threadIdx.x;
    int tile = blockIdx.x;           // 0..2047
    int b = tile >> 10;
    int p0 = (tile & 1023) << 6;
    int tx = tid & 15, ty = tid >> 4;

    float acc[8][4] = {};

    const float* fb = feature + (size_t)b * CIN * HWP;
    int wo = tid >> 1;               // 0..127 (o row to load)
    int kb = (tid & 1) * 8;          // kk base
    int fk = tid >> 4;               // 0..15
    int fp = (tid & 15) * 4;

    for (int k0 = 0; k0 < CIN; k0 += 16) {
        float4 wa = *(const float4*)(fc1_w + wo * CIN + k0 + kb);
        float4 wb2 = *(const float4*)(fc1_w + wo * CIN + k0 + kb + 4);
        sW[(kb + 0) * 132 + wo] = wa.x;
        sW[(kb + 1) * 132 + wo] = wa.y;
        sW[(kb + 2) * 132 + wo] = wa.z;
        sW[(kb + 3) * 132 + wo] = wa.w;
        sW[(kb + 4) * 132 + wo] = wb2.x;
        sW[(kb + 5) * 132 + wo] = wb2.y;
        sW[(kb + 6) * 132 + wo] = wb2.z;
        sW[(kb + 7) * 132 + wo] = wb2.w;
        float4 fv = *(const float4*)(fb + (size_t)(k0 + fk) * HWP + p0 + fp);
        *(float4*)(sF + fk * 64 + fp) = fv;
        __syncthreads();
#pragma unroll
        for (int kk = 0; kk < 16; kk++) {
            float4 f = *(float4*)(sF + kk * 64 + tx * 4);
            float4 wA = *(float4*)(sW + kk * 132 + ty * 8);
            float4 wB = *(float4*)(sW + kk * 132 + ty * 8 + 4);
            float fr[4] = { f.x, f.y, f.z, f.w };
            float wr[8] = { wA.x, wA.y, wA.z, wA.w, wB.x, wB.y, wB.z, wB.w };
#pragma unroll
            for (int i = 0; i < 8; i++)
#pragma unroll
                for (int j = 0; j < 4; j++)
                    acc[i][j] += wr[i] * fr[j];
        }
        __syncthreads();
    }

    float bias[8];
    *(float4*)bias = *(const float4*)(fc1_b + ty * 8);
    *(float4*)(bias + 4) = *(const float4*)(fc1_b + ty * 8 + 4);
    ushort* xrow = xout + (size_t)b * HWP * CLOI;
#pragma unroll
    for (int j = 0; j < 4; j++) {
        int p = p0 + tx * 4 + j;
        uint4 u;
        u.x = pack2(acc[0][j] + bias[0], acc[1][j] + bias[1]);
        u.y = pack2(acc[2][j] + bias[2], acc[3][j] + bias[3]);
        u.z = pack2(acc[4][j] + bias[4], acc[5][j] + bias[5]);
        u.w = pack2(acc[6][j] + bias[6], acc[7][j] + bias[7]);
        *(uint4*)(xrow + (size_t)p * CLOI + ty * 8) = u;
    }
}

// ---------------------------------------------------------------------------
// Kernel B1: bilinear sample 32 pts/line + MaxPool1d(4) -> xs[n][t][c] f32
// One block per line. Wave w handles j = w*8..w*8+7 (pool groups 2w, 2w+1).
// Lane owns channels {2*lane, 2*lane+1} via one uint (2 bf16) per pixel load.
// ---------------------------------------------------------------------------
__global__ __launch_bounds__(256) void sample_kernel(
    const ushort* __restrict__ x, const float* __restrict__ lines,
    float* __restrict__ xs)
{
    __shared__ int   sIdx[NPTS0][4];
    __shared__ float sWt[NPTS0][4];

    int n = blockIdx.x;
    int b = n / LL;
    int tid = threadIdx.x;

    if (tid < NPTS0) {
        int j = tid;
        float lam = (float)j * (1.0f / 31.0f);
        const float* lp = lines + (size_t)n * 4;
        float e0x = lp[0], e0y = lp[1], e1x = lp[2], e1y = lp[3];
        float px = e0x * lam + e1x * (1.f - lam) - 0.5f;
        float py = e0y * lam + e1y * (1.f - lam) - 0.5f;
        float px0 = fminf(fmaxf(floorf(px), 0.f), 255.f);
        float py0 = fminf(fmaxf(floorf(py), 0.f), 255.f);
        float px1 = fminf(px0 + 1.f, 255.f);
        float py1 = fminf(py0 + 1.f, 255.f);
        int ix0 = (int)px0, iy0 = (int)py0, ix1 = (int)px1, iy1 = (int)py1;
        sIdx[j][0] = ix0 * WW + iy0;
        sIdx[j][1] = ix1 * WW + iy0;
        sIdx[j][2] = ix0 * WW + iy1;
        sIdx[j][3] = ix1 * WW + iy1;
        sWt[j][0] = (px1 - px) * (py1 - py);
        sWt[j][1] = (px - px0) * (py1 - py);
        sWt[j][2] = (px1 - px) * (py - py0);
        sWt[j][3] = (px - px0) * (py - py0);
    }
    __syncthreads();

    int w = tid >> 6, lane = tid & 63;
    const uint* xb = (const uint*)(x + (size_t)b * HWP * CLOI);  // 64 uints per pixel

    float m00 = -INFINITY, m10 = -INFINITY;   // group 2w,   ch0/ch1
    float m01 = -INFINITY, m11 = -INFINITY;   // group 2w+1, ch0/ch1

#pragma unroll
    for (int jj = 0; jj < 8; jj++) {
        int j = w * 8 + jj;
        int i00 = sIdx[j][0], i10 = sIdx[j][1], i01 = sIdx[j][2], i11 = sIdx[j][3];
        float w00 = sWt[j][0], w10 = sWt[j][1], w01 = sWt[j][2], w11 = sWt[j][3];
        uint u00 = xb[(size_t)i00 * 64 + lane];
        uint u10 = xb[(size_t)i10 * 64 + lane];
        uint u01 = xb[(size_t)i01 * 64 + lane];
        uint u11 = xb[(size_t)i11 * 64 + lane];
        float v0 = bf2f((ushort)(u00 & 0xffff)) * w00 + bf2f((ushort)(u10 & 0xffff)) * w10
                 + bf2f((ushort)(u01 & 0xffff)) * w01 + bf2f((ushort)(u11 & 0xffff)) * w11;
        float v1 = bf2f((ushort)(u00 >> 16)) * w00 + bf2f((ushort)(u10 >> 16)) * w10
                 + bf2f((ushort)(u01 >> 16)) * w01 + bf2f((ushort)(u11 >> 16)) * w11;
        if (jj < 4) { m00 = fmaxf(m00, v0); m10 = fmaxf(m10, v1); }
        else        { m01 = fmaxf(m01, v0); m11 = fmaxf(m11, v1); }
    }

    float* base = xs + (size_t)n * (CLOI * NPTS1);
    float2 a; a.x = m00; a.y = m10;
    float2 c; c.x = m01; c.y = m11;
    *(float2*)(base + (2 * w + 0) * CLOI + 2 * lane) = a;
    *(float2*)(base + (2 * w + 1) * CLOI + 2 * lane) = c;
}

// ---------------------------------------------------------------------------
// Kernel B2: Bottleneck1D + fc2 head. 2 lines per block, 256 threads.
// Weights staged transposed (+pad) in one reusable LDS buffer; activation
// reads are wave-broadcast; conv reads are float4 from padded rows.
// ---------------------------------------------------------------------------
__global__ __launch_bounds__(256) void head_kernel(
    const float* __restrict__ xs,
    const float* __restrict__ bn1_g, const float* __restrict__ bn1_b,
    const float* __restrict__ bn1_m, const float* __restrict__ bn1_v,
    const float* __restrict__ conv1_w, const float* __restrict__ conv1_b,
    const float* __restrict__ bn2_g, const float* __restrict__ bn2_b,
    const float* __restrict__ bn2_m, const float* __restrict__ bn2_v,
    const float* __restrict__ conv2_w, const float* __restrict__ conv2_b,
    const float* __restrict__ bn3_g, const float* __restrict__ bn3_b,
    const float* __restrict__ bn3_m, const float* __restrict__ bn3_v,
    const float* __restrict__ conv3_w, const float* __restrict__ conv3_b,
    const float* __restrict__ fc2_w, const float* __restrict__ fc2_b,
    float* __restrict__ out)
{
    __shared__ float sW[128 * 68];      // reused: W1^T [128][68] / W2dt^T [64][68] / W3^T [64][132]
    __shared__ float s_xs[128 * 16];    // [c][l*8+t]
    __shared__ float s_h1[128 * 16];    // h1, later reused as relu(xp2)
    __shared__ float s_h3[64 * 16];
    __shared__ float s_h5[64 * 16];
    __shared__ float s_red[4 * 8];

    int tid = threadIdx.x;
    int n0 = blockIdx.x * 2;

    // ---- Phase 0: load xs (2 lines) into LDS [c][l*8+t]; stage W1^T ----
    const float4* xs4 = (const float4*)(xs + (size_t)n0 * (CLOI * NPTS1));
#pragma unroll
    for (int it = 0; it < 2; it++) {
        float4 v = xs4[it * 256 + tid];
        int e = (it * 256 + tid) * 4;     // l*1024 + t*128 + c
        int l = e >> 10, r = e & 1023, t = r >> 7, c = r & 127;
        float vv[4] = { v.x, v.y, v.z, v.w };
#pragma unroll
        for (int j = 0; j < 4; j++) s_xs[(c + j) * 16 + l * 8 + t] = vv[j];
    }
    const float4* w1_4 = (const float4*)conv1_w;  // [128][128]
#pragma unroll
    for (int it = 0; it < 8; it++) {
        int e4 = it * 256 + tid;          // 0..2047
        float4 v = w1_4[e4];
        int o = e4 >> 5;                  // row (o), 32 f4 per row
        int c0 = (e4 & 31) * 4;
        float vv[4] = { v.x, v.y, v.z, v.w };
#pragma unroll
        for (int j = 0; j < 4; j++) sW[(c0 + j) * 68 + o] = vv[j];
    }
    __syncthreads();

    // ---- Phase 1: h1 = relu(bn1(xs)) ----
    {
        int c = tid >> 1, half = tid & 1;
        float s1 = bn1_g[c] * rsqrtf(bn1_v[c] + EPSV);
        float t1 = bn1_b[c] - bn1_m[c] * s1;
#pragma unroll
        for (int i = 0; i < 8; i++) {
            int off = c * 16 + half * 8 + i;
            s_h1[off] = fmaxf(s_xs[off] * s1 + t1, 0.f);
        }
    }
    __syncthreads();

    int og = tid >> 4, lt = tid & 15;
    int l = lt >> 3, t = lt & 7;

    // ---- Phase 2: conv1 (k=1, 128->64) + bn2 + relu -> h3 ----
    {
        int o0 = og * 4;
        float4 acc = *(const float4*)(conv1_b + o0);
        for (int cc = 0; cc < 128; cc++) {
            float4 wv = *(float4*)(sW + cc * 68 + o0);
            float hv = s_h1[cc * 16 + lt];
            acc.x += wv.x * hv; acc.y += wv.y * hv;
            acc.z += wv.z * hv; acc.w += wv.w * hv;
        }
        float accs[4] = { acc.x, acc.y, acc.z, acc.w };
#pragma unroll
        for (int i = 0; i < 4; i++) {
            int o = o0 + i;
            float s2 = bn2_g[o] * rsqrtf(bn2_v[o] + EPSV);
            float t2 = bn2_b[o] - bn2_m[o] * s2;
            s_h3[o * 16 + lt] = fmaxf(accs[i] * s2 + t2, 0.f);
        }
    }
    __syncthreads();

    // ---- Phase 3: conv2 (k=3, pad 1, 64->64) + bn3 + relu -> h5 ----
    {
        int o0 = og * 4;
        float4 acc = *(const float4*)(conv2_b + o0);
        for (int dt = 0; dt < 3; dt++) {
            __syncthreads();
            // stage W2[dt]^T: sW[i][o], pad 68
            for (int it = 0; it < 16; it++) {
                int e = it * 256 + tid;
                int o = e >> 6, i = e & 63;
                sW[i * 68 + o] = conv2_w[o * 192 + i * 3 + dt];
            }
            __syncthreads();
            int ts = t + dt - 1;
            bool ok = ((unsigned)ts < 8u);
            for (int i = 0; i < 64; i++) {
                float hv = ok ? s_h3[i * 16 + l * 8 + ts] : 0.f;
                float4 wv = *(float4*)(sW + i * 68 + o0);
                acc.x += wv.x * hv; acc.y += wv.y * hv;
                acc.z += wv.z * hv; acc.w += wv.w * hv;
            }
        }
        float accs[4] = { acc.x, acc.y, acc.z, acc.w };
#pragma unroll
        for (int i = 0; i < 4; i++) {
            int o = o0 + i;
            float s3 = bn3_g[o] * rsqrtf(bn3_v[o] + EPSV);
            float t3 = bn3_b[o] - bn3_m[o] * s3;
            s_h5[o * 16 + lt] = fmaxf(accs[i] * s3 + t3, 0.f);
        }
    }
    __syncthreads();

    // ---- Phase 4: conv3 (k=1, 64->128), residual, relu -> reuse s_h1 ----
    {
        // stage W3^T: sW[c][o], pad 132
        const float4* w3_4 = (const float4*)conv3_w;  // [128][64]
#pragma unroll
        for (int it = 0; it < 8; it++) {
            int e4 = it * 256 + tid;
            float4 v = w3_4[e4];
            int o = e4 >> 4;              // 16 f4 per row
            int c0 = (e4 & 15) * 4;
            float vv[4] = { v.x, v.y, v.z, v.w };
#pragma unroll
            for (int j = 0; j < 4; j++) sW[(c0 + j) * 132 + o] = vv[j];
        }
        __syncthreads();

        int o0 = og * 8;
        float accv[8];
        *(float4*)(accv) = *(const float4*)(conv3_b + o0);
        *(float4*)(accv + 4) = *(const float4*)(conv3_b + o0 + 4);
        for (int cc = 0; cc < 64; cc++) {
            float hv = s_h5[cc * 16 + lt];
            float4 wa = *(float4*)(sW + cc * 132 + o0);
            float4 wb = *(float4*)(sW + cc * 132 + o0 + 4);
            accv[0] += wa.x * hv; accv[1] += wa.y * hv;
            accv[2] += wa.z * hv; accv[3] += wa.w * hv;
            accv[4] += wb.x * hv; accv[5] += wb.y * hv;
            accv[6] += wb.z * hv; accv[7] += wb.w * hv;
        }
        __syncthreads();   // everyone done reading s_h1 (it was read in phase 2 only) & safe to overwrite
#pragma unroll
        for (int i = 0; i < 8; i++) {
            int o = o0 + i;
            float r = s_xs[o * 16 + lt] + accv[i];
            s_h1[o * 16 + lt] = fmaxf(r, 0.f);
        }
    }
    __syncthreads();

    // ---- Phase 5: fc2 (1024 -> 3) for both lines ----
    {
        float p00 = 0.f, p01 = 0.f, p02 = 0.f, p10 = 0.f, p11 = 0.f, p12 = 0.f;
#pragma unroll
        for (int it = 0; it < 4; it++) {
            int idx = it * 256 + tid;     // c*8 + t
            int c = idx >> 3, tt = idx & 7;
            float w0 = fc2_w[idx];
            float w1 = fc2_w[1024 + idx];
            float w2 = fc2_w[2048 + idx];
            float r0 = s_h1[c * 16 + tt];
            float r1 = s_h1[c * 16 + 8 + tt];
            p00 += w0 * r0; p01 += w1 * r0; p02 += w2 * r0;
            p10 += w0 * r1; p11 += w1 * r1; p12 += w2 * r1;
        }
#pragma unroll
        for (int off = 32; off > 0; off >>= 1) {
            p00 += __shfl_down(p00, off);
            p01 += __shfl_down(p01, off);
            p02 += __shfl_down(p02, off);
            p10 += __shfl_down(p10, off);
            p11 += __shfl_down(p11, off);
            p12 += __shfl_down(p12, off);
        }
        if ((tid & 63) == 0) {
            int w = tid >> 6;
            s_red[w * 8 + 0] = p00; s_red[w * 8 + 1] = p01; s_red[w * 8 + 2] = p02;
            s_red[w * 8 + 3] = p10; s_red[w * 8 + 4] = p11; s_red[w * 8 + 5] = p12;
        }
        __syncthreads();
        if (tid < 6) {
            int li = tid / 3, k = tid % 3;
            float s = s_red[tid] + s_red[8 + tid] + s_red[16 + tid] + s_red[24 + tid];
            out[(size_t)(n0 + li) * 3 + k] = s + fc2_b[k];
        }
    }
}

extern "C" void kernel_launch(void* const* d_in, const int* in_sizes, int n_in,
                              void* d_out, int out_size, void* d_ws, size_t ws_size,
                              hipStream_t stream) {
    const float* feature = (const float*)d_in[0];
    const float* lines   = (const float*)d_in[1];
    const float* fc1_w   = (const float*)d_in[2];
    const float* fc1_b   = (const float*)d_in[3];
    const float* bn1_g   = (const float*)d_in[4];
    const float* bn1_b   = (const float*)d_in[5];
    const float* bn1_m   = (const float*)d_in[6];
    const float* bn1_v   = (const float*)d_in[7];
    const float* conv1_w = (const float*)d_in[8];
    const float* conv1_b = (const float*)d_in[9];
    const float* bn2_g   = (const float*)d_in[10];
    const float* bn2_b   = (const float*)d_in[11];
    const float* bn2_m   = (const float*)d_in[12];
    const float* bn2_v   = (const float*)d_in[13];
    const float* conv2_w = (const float*)d_in[14];
    const float* conv2_b = (const float*)d_in[15];
    const float* bn3_g   = (const float*)d_in[16];
    const float* bn3_b   = (const float*)d_in[17];
    const float* bn3_m   = (const float*)d_in[18];
    const float* bn3_v   = (const float*)d_in[19];
    const float* conv3_w = (const float*)d_in[20];
    const float* conv3_b = (const float*)d_in[21];
    const float* fc2_w   = (const float*)d_in[22];
    const float* fc2_b   = (const float*)d_in[23];
    float* out = (float*)d_out;

    ushort* x_bf = (ushort*)d_ws;
    float*  xs   = (float*)((char*)d_ws + X_BYTES);

    fc1_kernel<<<2048, 256, 0, stream>>>(feature, fc1_w, fc1_b, x_bf);
    sample_kernel<<<BB * LL, 256, 0, stream>>>(x_bf, lines, xs);
    head_kernel<<<BB * LL / 2, 256, 0, stream>>>(
        xs, bn1_g, bn1_b, bn1_m, bn1_v, conv1_w, conv1_b,
        bn2_g, bn2_b, bn2_m, bn2_v, conv2_w, conv2_b,
        bn3_g, bn3_b, bn3_m, bn3_v, conv3_w, conv3_b,
        fc2_w, fc2_b, out);
}

// Round 2
// 371.098 us; speedup vs baseline: 4.9433x; 4.9433x over previous
//
#include <hip/hip_runtime.h>
#include <hip/hip_bf16.h>

// Problem constants
#define BB 2
#define LL 5000
#define CIN 256
#define CLOI 128
#define HH 256
#define WW 256
#define HWP (HH*WW)
#define NPTS0 32
#define NPTS1 8
#define PLANES 64
#define EPSV 1e-5f

// workspace layout (bytes)
#define X_BYTES   ((size_t)BB * HWP * CLOI * 2)            // 33,554,432: fc1 map bf16 channel-last
#define XS_BYTES  ((size_t)BB * LL * 1024 * 2)             // 20,480,000: xs bf16 swizzled [line][kg16][t8][8]
#define W1S_OFF   (X_BYTES + XS_BYTES)                     // 8192 bf16 = 16384 B   [16kg][64m][8]
#define W2S_OFF   (W1S_OFF + 16384)                        // 12288 bf16 = 24576 B  [3dt][8kg][64m][8]
#define W3S_OFF   (W2S_OFF + 24576)                        // 8192 bf16 = 16384 B   [8kg][128m][8]
#define B1P_OFF   (W3S_OFF + 16384)                        // 64 f32
#define B2P_OFF   (B1P_OFF + 256)                          // 64 f32
#define S1_OFF    (B2P_OFF + 256)                          // 128 f32
#define T1_OFF    (S1_OFF + 512)                           // 128 f32

typedef unsigned int uint;
typedef unsigned short ushort;
typedef __attribute__((ext_vector_type(8))) short short8;
typedef __attribute__((ext_vector_type(4))) float f32x4;

__device__ __forceinline__ float bf2f(ushort u) {
    uint v = ((uint)u) << 16;
    return __uint_as_float(v);
}
__device__ __forceinline__ ushort f2bf(float f) {
    uint x = __float_as_uint(f);
    uint r = (x + 0x7fffu + ((x >> 16) & 1u)) >> 16;   // RNE
    return (ushort)r;
}
__device__ __forceinline__ uint pack2(float a, float b) {
    return (uint)f2bf(a) | ((uint)f2bf(b) << 16);
}

// ---------------------------------------------------------------------------
// Kernel A: fc1 1x1 conv as GEMM -> bf16 channel-last map (unchanged, passed R1)
// ---------------------------------------------------------------------------
__global__ __launch_bounds__(256) void fc1_kernel(
    const float* __restrict__ feature, const float* __restrict__ fc1_w,
    const float* __restrict__ fc1_b, ushort* __restrict__ xout)
{
    __shared__ float sW[16 * 132];
    __shared__ float sF[16 * 64];

    int tid = threadIdx.x;
    int tile = blockIdx.x;
    int b = tile >> 10;
    int p0 = (tile & 1023) << 6;
    int tx = tid & 15, ty = tid >> 4;

    float acc[8][4] = {};

    const float* fb = feature + (size_t)b * CIN * HWP;
    int wo = tid >> 1;
    int kb = (tid & 1) * 8;
    int fk = tid >> 4;
    int fp = (tid & 15) * 4;

    for (int k0 = 0; k0 < CIN; k0 += 16) {
        float4 wa = *(const float4*)(fc1_w + wo * CIN + k0 + kb);
        float4 wb2 = *(const float4*)(fc1_w + wo * CIN + k0 + kb + 4);
        sW[(kb + 0) * 132 + wo] = wa.x;
        sW[(kb + 1) * 132 + wo] = wa.y;
        sW[(kb + 2) * 132 + wo] = wa.z;
        sW[(kb + 3) * 132 + wo] = wa.w;
        sW[(kb + 4) * 132 + wo] = wb2.x;
        sW[(kb + 5) * 132 + wo] = wb2.y;
        sW[(kb + 6) * 132 + wo] = wb2.z;
        sW[(kb + 7) * 132 + wo] = wb2.w;
        float4 fv = *(const float4*)(fb + (size_t)(k0 + fk) * HWP + p0 + fp);
        *(float4*)(sF + fk * 64 + fp) = fv;
        __syncthreads();
#pragma unroll
        for (int kk = 0; kk < 16; kk++) {
            float4 f = *(float4*)(sF + kk * 64 + tx * 4);
            float4 wA = *(float4*)(sW + kk * 132 + ty * 8);
            float4 wB = *(float4*)(sW + kk * 132 + ty * 8 + 4);
            float fr[4] = { f.x, f.y, f.z, f.w };
            float wr[8] = { wA.x, wA.y, wA.z, wA.w, wB.x, wB.y, wB.z, wB.w };
#pragma unroll
            for (int i = 0; i < 8; i++)
#pragma unroll
                for (int j = 0; j < 4; j++)
                    acc[i][j] += wr[i] * fr[j];
        }
        __syncthreads();
    }

    float bias[8];
    *(float4*)bias = *(const float4*)(fc1_b + ty * 8);
    *(float4*)(bias + 4) = *(const float4*)(fc1_b + ty * 8 + 4);
    ushort* xrow = xout + (size_t)b * HWP * CLOI;
#pragma unroll
    for (int j = 0; j < 4; j++) {
        int p = p0 + tx * 4 + j;
        uint4 u;
        u.x = pack2(acc[0][j] + bias[0], acc[1][j] + bias[1]);
        u.y = pack2(acc[2][j] + bias[2], acc[3][j] + bias[3]);
        u.z = pack2(acc[4][j] + bias[4], acc[5][j] + bias[5]);
        u.w = pack2(acc[6][j] + bias[6], acc[7][j] + bias[7]);
        *(uint4*)(xrow + (size_t)p * CLOI + ty * 8) = u;
    }
}

// ---------------------------------------------------------------------------
// Prep kernel: fold bn2->conv1, bn3->conv2; convert conv weights to bf16 in
// MFMA A-frag swizzled layout [kg][m][8]; emit bn1 scale/shift.
// ---------------------------------------------------------------------------
__global__ __launch_bounds__(256) void prep_kernel(
    const float* __restrict__ conv1_w, const float* __restrict__ conv1_b,
    const float* __restrict__ bn2_g, const float* __restrict__ bn2_b,
    const float* __restrict__ bn2_m, const float* __restrict__ bn2_v,
    const float* __restrict__ conv2_w, const float* __restrict__ conv2_b,
    const float* __restrict__ bn3_g, const float* __restrict__ bn3_b,
    const float* __restrict__ bn3_m, const float* __restrict__ bn3_v,
    const float* __restrict__ conv3_w,
    const float* __restrict__ bn1_g, const float* __restrict__ bn1_b,
    const float* __restrict__ bn1_m, const float* __restrict__ bn1_v,
    ushort* __restrict__ w1s, ushort* __restrict__ w2s, ushort* __restrict__ w3s,
    float* __restrict__ b1p, float* __restrict__ b2p,
    float* __restrict__ s1o, float* __restrict__ t1o)
{
    int idx = blockIdx.x * 256 + threadIdx.x;
    if (idx < 8192) {   // W1s [16kg][64m][8], fold s2
        int kg = idx >> 9, rem = idx & 511, m = rem >> 3, j = rem & 7;
        int c = kg * 8 + j;
        float s2 = bn2_g[m] * rsqrtf(bn2_v[m] + EPSV);
        w1s[idx] = f2bf(conv1_w[m * 128 + c] * s2);
    }
    if (idx < 12288) {  // W2s [3dt][8kg][64m][8], fold s3
        int dt = idx >> 12, rem = idx & 4095;
        int kg = rem >> 9, m = (rem >> 3) & 63, j = rem & 7;
        int i = kg * 8 + j;
        float s3 = bn3_g[m] * rsqrtf(bn3_v[m] + EPSV);
        w2s[idx] = f2bf(conv2_w[m * 192 + i * 3 + dt] * s3);
    }
    if (idx < 8192) {   // W3s [8kg][128m][8]
        int kg = idx >> 10, rem = idx & 1023, m = rem >> 3, j = rem & 7;
        w3s[idx] = f2bf(conv3_w[m * 64 + kg * 8 + j]);
    }
    if (idx < 64) {
        float s2 = bn2_g[idx] * rsqrtf(bn2_v[idx] + EPSV);
        b1p[idx] = conv1_b[idx] * s2 + bn2_b[idx] - bn2_m[idx] * s2;
        float s3 = bn3_g[idx] * rsqrtf(bn3_v[idx] + EPSV);
        b2p[idx] = conv2_b[idx] * s3 + bn3_b[idx] - bn3_m[idx] * s3;
    }
    if (idx < 128) {
        float s1 = bn1_g[idx] * rsqrtf(bn1_v[idx] + EPSV);
        s1o[idx] = s1;
        t1o[idx] = bn1_b[idx] - bn1_m[idx] * s1;
    }
}

// ---------------------------------------------------------------------------
// Kernel B1: bilinear sample + maxpool -> xs bf16 swizzled [line][kg16][t8][8]
// ---------------------------------------------------------------------------
__global__ __launch_bounds__(256) void sample_kernel(
    const ushort* __restrict__ x, const float* __restrict__ lines,
    ushort* __restrict__ xsb)
{
    __shared__ int   sIdx[NPTS0][4];
    __shared__ float sWt[NPTS0][4];

    int n = blockIdx.x;
    int b = n / LL;
    int tid = threadIdx.x;

    if (tid < NPTS0) {
        int j = tid;
        float lam = (float)j * (1.0f / 31.0f);
        const float* lp = lines + (size_t)n * 4;
        float e0x = lp[0], e0y = lp[1], e1x = lp[2], e1y = lp[3];
        float px = e0x * lam + e1x * (1.f - lam) - 0.5f;
        float py = e0y * lam + e1y * (1.f - lam) - 0.5f;
        float px0 = fminf(fmaxf(floorf(px), 0.f), 255.f);
        float py0 = fminf(fmaxf(floorf(py), 0.f), 255.f);
        float px1 = fminf(px0 + 1.f, 255.f);
        float py1 = fminf(py0 + 1.f, 255.f);
        int ix0 = (int)px0, iy0 = (int)py0, ix1 = (int)px1, iy1 = (int)py1;
        sIdx[j][0] = ix0 * WW + iy0;
        sIdx[j][1] = ix1 * WW + iy0;
        sIdx[j][2] = ix0 * WW + iy1;
        sIdx[j][3] = ix1 * WW + iy1;
        sWt[j][0] = (px1 - px) * (py1 - py);
        sWt[j][1] = (px - px0) * (py1 - py);
        sWt[j][2] = (px1 - px) * (py - py0);
        sWt[j][3] = (px - px0) * (py - py0);
    }
    __syncthreads();

    int w = tid >> 6, lane = tid & 63;
    const uint* xb = (const uint*)(x + (size_t)b * HWP * CLOI);

    float m00 = -INFINITY, m10 = -INFINITY;
    float m01 = -INFINITY, m11 = -INFINITY;

#pragma unroll
    for (int jj = 0; jj < 8; jj++) {
        int j = w * 8 + jj;
        int i00 = sIdx[j][0], i10 = sIdx[j][1], i01 = sIdx[j][2], i11 = sIdx[j][3];
        float w00 = sWt[j][0], w10 = sWt[j][1], w01 = sWt[j][2], w11 = sWt[j][3];
        uint u00 = xb[(size_t)i00 * 64 + lane];
        uint u10 = xb[(size_t)i10 * 64 + lane];
        uint u01 = xb[(size_t)i01 * 64 + lane];
        uint u11 = xb[(size_t)i11 * 64 + lane];
        float v0 = bf2f((ushort)(u00 & 0xffff)) * w00 + bf2f((ushort)(u10 & 0xffff)) * w10
                 + bf2f((ushort)(u01 & 0xffff)) * w01 + bf2f((ushort)(u11 & 0xffff)) * w11;
        float v1 = bf2f((ushort)(u00 >> 16)) * w00 + bf2f((ushort)(u10 >> 16)) * w10
                 + bf2f((ushort)(u01 >> 16)) * w01 + bf2f((ushort)(u11 >> 16)) * w11;
        if (jj < 4) { m00 = fmaxf(m00, v0); m10 = fmaxf(m10, v1); }
        else        { m01 = fmaxf(m01, v0); m11 = fmaxf(m11, v1); }
    }

    // write: channels c0=2*lane, c0+1; el = kg*64 + t*8 + j
    ushort* basep = xsb + (size_t)n * 1024;
    int kg = lane >> 2;
    int j2 = (lane & 3) * 2;
    *(uint*)(basep + kg * 64 + (2 * w) * 8 + j2) = pack2(m00, m10);
    *(uint*)(basep + kg * 64 + (2 * w + 1) * 8 + j2) = pack2(m01, m11);
}

// ---------------------------------------------------------------------------
// Kernel B2: MFMA head. 8 lines/block, 4 waves, wave w owns cols w*16..w*16+15
// (col = l*8 + t). conv1/conv2(3 taps)/conv3 as 16x16x32 bf16 MFMA; residual +
// relu + fc2 per-lane fp32 with shuffle reduce.
// ---------------------------------------------------------------------------
__global__ __launch_bounds__(256) void head_kernel(
    const ushort* __restrict__ xsb,
    const ushort* __restrict__ w1s, const ushort* __restrict__ w2s,
    const ushort* __restrict__ w3s,
    const float* __restrict__ b1p, const float* __restrict__ b2p,
    const float* __restrict__ s1g, const float* __restrict__ t1g,
    const float* __restrict__ conv3_b,
    const float* __restrict__ fc2_w, const float* __restrict__ fc2_b,
    float* __restrict__ out)
{
    __shared__ ushort sXS[8192];   // [16kg][64col][8] raw xs bf16
    __shared__ ushort sH1[8192];   // h1; first 4096 reused as B3 (conv2 out)
    __shared__ ushort sB2[4096];   // [8kg][64col][8] conv1 out
    __shared__ float  sFC2[3072];  // fc2_w
    __shared__ float  sS1[128], sT1[128];
    __shared__ float  sB1[64], sB2b[64], sB3b[128];

    int tid = threadIdx.x;
    int wv = tid >> 6, lane = tid & 63;
    int q = lane >> 4, ln = lane & 15;
    int L0 = blockIdx.x * 8;
    int colg = wv * 16 + ln;

    // ---- params to LDS ----
    if (tid < 128) { sS1[tid] = s1g[tid]; sT1[tid] = t1g[tid]; sB3b[tid] = conv3_b[tid]; }
    if (tid < 64)  { sB1[tid] = b1p[tid]; sB2b[tid] = b2p[tid]; }
#pragma unroll
    for (int it = 0; it < 12; it++) sFC2[it * 256 + tid] = fc2_w[it * 256 + tid];
    __syncthreads();

    // ---- stage xs tile + compute h1 = relu(bn1(xs)) ----
#pragma unroll
    for (int it = 0; it < 4; it++) {
        int ch = it * 256 + tid;          // 0..1023
        int l = ch >> 7, wc = ch & 127;
        int kg = wc >> 3, tt = wc & 7;
        int col = l * 8 + tt;
        uint4 raw = *(const uint4*)(xsb + (size_t)(L0 + l) * 1024 + wc * 8);
        int off = (kg * 64 + col) * 8;
        *(uint4*)(&sXS[off]) = raw;
        uint rw[4] = { raw.x, raw.y, raw.z, raw.w };
        uint hw[4];
#pragma unroll
        for (int p = 0; p < 4; p++) {
            int c = kg * 8 + p * 2;
            float v0 = bf2f((ushort)(rw[p] & 0xffff));
            float v1 = bf2f((ushort)(rw[p] >> 16));
            float h0 = fmaxf(v0 * sS1[c] + sT1[c], 0.f);
            float h1v = fmaxf(v1 * sS1[c + 1] + sT1[c + 1], 0.f);
            hw[p] = pack2(h0, h1v);
        }
        uint4 hv; hv.x = hw[0]; hv.y = hw[1]; hv.z = hw[2]; hv.w = hw[3];
        *(uint4*)(&sH1[off]) = hv;
    }
    __syncthreads();

    const short8 bzero = { 0, 0, 0, 0, 0, 0, 0, 0 };
    const f32x4 fzero = { 0.f, 0.f, 0.f, 0.f };

    // ---- conv1: M=64, K=128 ----
    f32x4 acc1[4];
#pragma unroll
    for (int mt = 0; mt < 4; mt++) acc1[mt] = fzero;
#pragma unroll
    for (int ks = 0; ks < 4; ks++) {
        short8 b = *(short8*)(&sH1[((ks * 4 + q) * 64 + colg) * 8]);
#pragma unroll
        for (int mt = 0; mt < 4; mt++) {
            short8 a = *(const short8*)(w1s + ((ks * 4 + q) * 64 + mt * 16 + ln) * 8);
            acc1[mt] = __builtin_amdgcn_mfma_f32_16x16x32_bf16(a, b, acc1[mt], 0, 0, 0);
        }
    }
    // epilogue -> sB2
#pragma unroll
    for (int mt = 0; mt < 4; mt++) {
        int m0 = mt * 16 + q * 4;
        float v0 = fmaxf(acc1[mt][0] + sB1[m0 + 0], 0.f);
        float v1 = fmaxf(acc1[mt][1] + sB1[m0 + 1], 0.f);
        float v2 = fmaxf(acc1[mt][2] + sB1[m0 + 2], 0.f);
        float v3 = fmaxf(acc1[mt][3] + sB1[m0 + 3], 0.f);
        uint2 u; u.x = pack2(v0, v1); u.y = pack2(v2, v3);
        *(uint2*)(&sB2[((m0 >> 3) * 64 + colg) * 8 + (m0 & 7)]) = u;
    }
    __syncthreads();

    // ---- conv2: M=64, K=64 x 3 taps (shifted cols, zero at line edges) ----
    f32x4 acc2[4];
#pragma unroll
    for (int mt = 0; mt < 4; mt++) acc2[mt] = fzero;
    int tpos = colg & 7;
#pragma unroll
    for (int dt = 0; dt < 3; dt++) {
        int tsh = tpos + dt - 1;
        bool valid = ((unsigned)tsh < 8u);
        int colr = colg + dt - 1;
        colr = colr < 0 ? 0 : (colr > 63 ? 63 : colr);
#pragma unroll
        for (int ks = 0; ks < 2; ks++) {
            short8 b = *(short8*)(&sB2[((ks * 4 + q) * 64 + colr) * 8]);
            b = valid ? b : bzero;
#pragma unroll
            for (int mt = 0; mt < 4; mt++) {
                short8 a = *(const short8*)(w2s + dt * 4096 + ((ks * 4 + q) * 64 + mt * 16 + ln) * 8);
                acc2[mt] = __builtin_amdgcn_mfma_f32_16x16x32_bf16(a, b, acc2[mt], 0, 0, 0);
            }
        }
    }
    // epilogue -> B3 (reuse sH1; all waves are past conv1 reads due to barrier)
#pragma unroll
    for (int mt = 0; mt < 4; mt++) {
        int m0 = mt * 16 + q * 4;
        float v0 = fmaxf(acc2[mt][0] + sB2b[m0 + 0], 0.f);
        float v1 = fmaxf(acc2[mt][1] + sB2b[m0 + 1], 0.f);
        float v2 = fmaxf(acc2[mt][2] + sB2b[m0 + 2], 0.f);
        float v3 = fmaxf(acc2[mt][3] + sB2b[m0 + 3], 0.f);
        uint2 u; u.x = pack2(v0, v1); u.y = pack2(v2, v3);
        *(uint2*)(&sH1[((m0 >> 3) * 64 + colg) * 8 + (m0 & 7)]) = u;
    }
    __syncthreads();

    // ---- conv3: M=128, K=64 ----
    f32x4 acc3[8];
#pragma unroll
    for (int mt = 0; mt < 8; mt++) acc3[mt] = fzero;
#pragma unroll
    for (int ks = 0; ks < 2; ks++) {
        short8 b = *(short8*)(&sH1[((ks * 4 + q) * 64 + colg) * 8]);
#pragma unroll
        for (int mt = 0; mt < 8; mt++) {
            short8 a = *(const short8*)(w3s + ((ks * 4 + q) * 128 + mt * 16 + ln) * 8);
            acc3[mt] = __builtin_amdgcn_mfma_f32_16x16x32_bf16(a, b, acc3[mt], 0, 0, 0);
        }
    }

    // ---- residual + relu + fc2 (per-lane fp32) ----
    float p0 = 0.f, p1 = 0.f, p2 = 0.f;
#pragma unroll
    for (int mt = 0; mt < 8; mt++) {
#pragma unroll
        for (int r = 0; r < 4; r++) {
            int m = mt * 16 + q * 4 + r;
            float xsv = bf2f(sXS[(m >> 3) * 512 + colg * 8 + (m & 7)]);
            float v = fmaxf(xsv + acc3[mt][r] + sB3b[m], 0.f);
            int fi = m * 8 + tpos;
            p0 += v * sFC2[fi];
            p1 += v * sFC2[1024 + fi];
            p2 += v * sFC2[2048 + fi];
        }
    }
    // reduce across quads (lane bits 4,5) then across t (bits 0,1,2)
    p0 += __shfl_xor(p0, 32); p1 += __shfl_xor(p1, 32); p2 += __shfl_xor(p2, 32);
    p0 += __shfl_xor(p0, 16); p1 += __shfl_xor(p1, 16); p2 += __shfl_xor(p2, 16);
    p0 += __shfl_xor(p0, 4);  p1 += __shfl_xor(p1, 4);  p2 += __shfl_xor(p2, 4);
    p0 += __shfl_xor(p0, 2);  p1 += __shfl_xor(p1, 2);  p2 += __shfl_xor(p2, 2);
    p0 += __shfl_xor(p0, 1);  p1 += __shfl_xor(p1, 1);  p2 += __shfl_xor(p2, 1);

    if (lane == 0 || lane == 8) {
        int line = L0 + wv * 2 + (lane >> 3);
        out[(size_t)line * 3 + 0] = p0 + fc2_b[0];
        out[(size_t)line * 3 + 1] = p1 + fc2_b[1];
        out[(size_t)line * 3 + 2] = p2 + fc2_b[2];
    }
}

extern "C" void kernel_launch(void* const* d_in, const int* in_sizes, int n_in,
                              void* d_out, int out_size, void* d_ws, size_t ws_size,
                              hipStream_t stream) {
    const float* feature = (const float*)d_in[0];
    const float* lines   = (const float*)d_in[1];
    const float* fc1_w   = (const float*)d_in[2];
    const float* fc1_b   = (const float*)d_in[3];
    const float* bn1_g   = (const float*)d_in[4];
    const float* bn1_b   = (const float*)d_in[5];
    const float* bn1_m   = (const float*)d_in[6];
    const float* bn1_v   = (const float*)d_in[7];
    const float* conv1_w = (const float*)d_in[8];
    const float* conv1_b = (const float*)d_in[9];
    const float* bn2_g   = (const float*)d_in[10];
    const float* bn2_b   = (const float*)d_in[11];
    const float* bn2_m   = (const float*)d_in[12];
    const float* bn2_v   = (const float*)d_in[13];
    const float* conv2_w = (const float*)d_in[14];
    const float* conv2_b = (const float*)d_in[15];
    const float* bn3_g   = (const float*)d_in[16];
    const float* bn3_b   = (const float*)d_in[17];
    const float* bn3_m   = (const float*)d_in[18];
    const float* bn3_v   = (const float*)d_in[19];
    const float* conv3_w = (const float*)d_in[20];
    const float* conv3_b = (const float*)d_in[21];
    const float* fc2_w   = (const float*)d_in[22];
    const float* fc2_b   = (const float*)d_in[23];
    float* out = (float*)d_out;

    char* ws = (char*)d_ws;
    ushort* x_bf = (ushort*)ws;
    ushort* xs_b = (ushort*)(ws + X_BYTES);
    ushort* w1s  = (ushort*)(ws + W1S_OFF);
    ushort* w2s  = (ushort*)(ws + W2S_OFF);
    ushort* w3s  = (ushort*)(ws + W3S_OFF);
    float*  b1p  = (float*)(ws + B1P_OFF);
    float*  b2p  = (float*)(ws + B2P_OFF);
    float*  s1g  = (float*)(ws + S1_OFF);
    float*  t1g  = (float*)(ws + T1_OFF);

    prep_kernel<<<48, 256, 0, stream>>>(
        conv1_w, conv1_b, bn2_g, bn2_b, bn2_m, bn2_v,
        conv2_w, conv2_b, bn3_g, bn3_b, bn3_m, bn3_v,
        conv3_w, bn1_g, bn1_b, bn1_m, bn1_v,
        w1s, w2s, w3s, b1p, b2p, s1g, t1g);
    fc1_kernel<<<2048, 256, 0, stream>>>(feature, fc1_w, fc1_b, x_bf);
    sample_kernel<<<BB * LL, 256, 0, stream>>>(x_bf, lines, xs_b);
    head_kernel<<<BB * LL / 8, 256, 0, stream>>>(
        xs_b, w1s, w2s, w3s, b1p, b2p, s1g, t1g, conv3_b, fc2_w, fc2_b, out);
}

// Round 3
// 299.273 us; speedup vs baseline: 6.1297x; 1.2400x over previous
//
#include <hip/hip_runtime.h>
#include <hip/hip_bf16.h>

// Problem constants
#define BB 2
#define LL 5000
#define CIN 256
#define CLOI 128
#define HH 256
#define WW 256
#define HWP (HH*WW)
#define NPTS0 32
#define NPTS1 8
#define PLANES 64
#define EPSV 1e-5f

// workspace layout (bytes)
#define X_BYTES   ((size_t)BB * HWP * CLOI * 2)            // 33,554,432: fc1 map bf16 channel-last
#define XS_BYTES  ((size_t)BB * LL * 1024 * 2)             // 20,480,000: xs bf16 swizzled [line][kg16][t8][8]
#define W1S_OFF   (X_BYTES + XS_BYTES)                     // 8192 bf16 = 16384 B   [16kg][64m][8]
#define W2S_OFF   (W1S_OFF + 16384)                        // 12288 bf16 = 24576 B  [3dt][8kg][64m][8]
#define W3S_OFF   (W2S_OFF + 24576)                        // 8192 bf16 = 16384 B   [8kg][128m][8]
#define B1P_OFF   (W3S_OFF + 16384)                        // 64 f32
#define B2P_OFF   (B1P_OFF + 256)                          // 64 f32
#define S1_OFF    (B2P_OFF + 256)                          // 128 f32
#define T1_OFF    (S1_OFF + 512)                           // 128 f32
#define W0S_OFF   (T1_OFF + 512)                           // fc1_w bf16 swizzled [32grp][128m][8] = 65536 B

typedef unsigned int uint;
typedef unsigned short ushort;
typedef __attribute__((ext_vector_type(8))) short short8;
typedef __attribute__((ext_vector_type(4))) float f32x4;

__device__ __forceinline__ float bf2f(ushort u) {
    uint v = ((uint)u) << 16;
    return __uint_as_float(v);
}
__device__ __forceinline__ ushort f2bf(float f) {
    uint x = __float_as_uint(f);
    uint r = (x + 0x7fffu + ((x >> 16) & 1u)) >> 16;   // RNE
    return (ushort)r;
}
__device__ __forceinline__ uint pack2(float a, float b) {
    return (uint)f2bf(a) | ((uint)f2bf(b) << 16);
}

// ---------------------------------------------------------------------------
// Kernel A: fc1 1x1 conv as bf16 MFMA GEMM.
// Block = 64 pixels x 128 outputs x K=256, single LDS stage + 1 barrier.
// Wave wv owns outputs wv*32..wv*32+31 (A-frags preloaded in registers).
// ---------------------------------------------------------------------------
__global__ __launch_bounds__(256) void fc1_kernel(
    const float* __restrict__ feature, const ushort* __restrict__ w0s,
    const float* __restrict__ fc1_b, ushort* __restrict__ xout)
{
    __shared__ ushort sF[32 * 64 * 8];   // [grp(k/8)][px][j] bf16, 32 KB

    int tid = threadIdx.x;
    int tile = blockIdx.x;               // 0..2047
    int b = tile >> 10;
    int p0 = (tile & 1023) << 6;
    int wv = tid >> 6, lane = tid & 63;
    int q = lane >> 4, ln = lane & 15;

    // preload A-frags: afr[kg][mt], k = kg*32 + q*8 + j, m = wv*32 + mt*16 + ln
    short8 afr[8][2];
#pragma unroll
    for (int kg = 0; kg < 8; kg++)
#pragma unroll
        for (int mt = 0; mt < 2; mt++)
            afr[kg][mt] = *(const short8*)(w0s + ((size_t)((kg * 4 + q) * 128 + wv * 32 + mt * 16 + ln)) * 8);

    // stage feature tile -> bf16 LDS (B-frag layout)
    const float* fb = feature + (size_t)b * CIN * HWP + p0;
    int g_ = tid >> 4;                   // 0..15 (channel group within pass)
    int qd = tid & 15;                   // pixel quad
#pragma unroll
    for (int s = 0; s < 2; s++) {
        int g = s * 16 + g_;             // channel group 0..31 (8 ch each)
        const float* src = fb + (size_t)(g * 8) * HWP + qd * 4;
        float4 rv[8];
#pragma unroll
        for (int j = 0; j < 8; j++) rv[j] = *(const float4*)(src + (size_t)j * HWP);
#pragma unroll
        for (int i = 0; i < 4; i++) {
            uint4 u;
            u.x = pack2(((const float*)&rv[0])[i], ((const float*)&rv[1])[i]);
            u.y = pack2(((const float*)&rv[2])[i], ((const float*)&rv[3])[i]);
            u.z = pack2(((const float*)&rv[4])[i], ((const float*)&rv[5])[i]);
            u.w = pack2(((const float*)&rv[6])[i], ((const float*)&rv[7])[i]);
            *(uint4*)(&sF[(g * 64 + qd * 4 + i) * 8]) = u;
        }
    }
    __syncthreads();

    const f32x4 fzero = { 0.f, 0.f, 0.f, 0.f };
    f32x4 acc[2][4];
#pragma unroll
    for (int mt = 0; mt < 2; mt++)
#pragma unroll
        for (int nt = 0; nt < 4; nt++) acc[mt][nt] = fzero;

#pragma unroll
    for (int kg = 0; kg < 8; kg++) {
#pragma unroll
        for (int nt = 0; nt < 4; nt++) {
            short8 bfr = *(short8*)(&sF[((kg * 4 + q) * 64 + nt * 16 + ln) * 8]);
            acc[0][nt] = __builtin_amdgcn_mfma_f32_16x16x32_bf16(afr[kg][0], bfr, acc[0][nt], 0, 0, 0);
            acc[1][nt] = __builtin_amdgcn_mfma_f32_16x16x32_bf16(afr[kg][1], bfr, acc[1][nt], 0, 0, 0);
        }
    }

    // epilogue: bias + pack + store. o = wv*32 + mt*16 + q*4 + r, p = p0 + nt*16 + ln
    float bias[8];
    *(float4*)bias       = *(const float4*)(fc1_b + wv * 32 + q * 4);
    *(float4*)(bias + 4) = *(const float4*)(fc1_b + wv * 32 + 16 + q * 4);
    ushort* xrow = xout + (size_t)b * HWP * CLOI;
#pragma unroll
    for (int mt = 0; mt < 2; mt++)
#pragma unroll
        for (int nt = 0; nt < 4; nt++) {
            uint2 u;
            u.x = pack2(acc[mt][nt][0] + bias[mt * 4 + 0], acc[mt][nt][1] + bias[mt * 4 + 1]);
            u.y = pack2(acc[mt][nt][2] + bias[mt * 4 + 2], acc[mt][nt][3] + bias[mt * 4 + 3]);
            *(uint2*)(xrow + (size_t)(p0 + nt * 16 + ln) * CLOI + wv * 32 + mt * 16 + q * 4) = u;
        }
}

// ---------------------------------------------------------------------------
// Prep kernel: fold bn2->conv1, bn3->conv2; convert conv weights to bf16 in
// MFMA A-frag swizzled layout [kg][m][8]; emit bn1 scale/shift; swizzle fc1_w.
// grid = 128 blocks x 256.
// ---------------------------------------------------------------------------
__global__ __launch_bounds__(256) void prep_kernel(
    const float* __restrict__ conv1_w, const float* __restrict__ conv1_b,
    const float* __restrict__ bn2_g, const float* __restrict__ bn2_b,
    const float* __restrict__ bn2_m, const float* __restrict__ bn2_v,
    const float* __restrict__ conv2_w, const float* __restrict__ conv2_b,
    const float* __restrict__ bn3_g, const float* __restrict__ bn3_b,
    const float* __restrict__ bn3_m, const float* __restrict__ bn3_v,
    const float* __restrict__ conv3_w,
    const float* __restrict__ bn1_g, const float* __restrict__ bn1_b,
    const float* __restrict__ bn1_m, const float* __restrict__ bn1_v,
    const float* __restrict__ fc1_w,
    ushort* __restrict__ w1s, ushort* __restrict__ w2s, ushort* __restrict__ w3s,
    float* __restrict__ b1p, float* __restrict__ b2p,
    float* __restrict__ s1o, float* __restrict__ t1o,
    ushort* __restrict__ w0s)
{
    int idx = blockIdx.x * 256 + threadIdx.x;
    if (idx < 8192) {   // W1s [16kg][64m][8], fold s2
        int kg = idx >> 9, rem = idx & 511, m = rem >> 3, j = rem & 7;
        int c = kg * 8 + j;
        float s2 = bn2_g[m] * rsqrtf(bn2_v[m] + EPSV);
        w1s[idx] = f2bf(conv1_w[m * 128 + c] * s2);
    }
    if (idx < 12288) {  // W2s [3dt][8kg][64m][8], fold s3
        int dt = idx >> 12, rem = idx & 4095;
        int kg = rem >> 9, m = (rem >> 3) & 63, j = rem & 7;
        int i = kg * 8 + j;
        float s3 = bn3_g[m] * rsqrtf(bn3_v[m] + EPSV);
        w2s[idx] = f2bf(conv2_w[m * 192 + i * 3 + dt] * s3);
    }
    if (idx < 8192) {   // W3s [8kg][128m][8]
        int kg = idx >> 10, rem = idx & 1023, m = rem >> 3, j = rem & 7;
        w3s[idx] = f2bf(conv3_w[m * 64 + kg * 8 + j]);
    }
    if (idx < 32768) {  // W0s [32grp][128m][8] from fc1_w [128m][256c]
        int grp = idx >> 10, rem = idx & 1023, m = rem >> 3, j = rem & 7;
        w0s[idx] = f2bf(fc1_w[m * CIN + grp * 8 + j]);
    }
    if (idx < 64) {
        float s2 = bn2_g[idx] * rsqrtf(bn2_v[idx] + EPSV);
        b1p[idx] = conv1_b[idx] * s2 + bn2_b[idx] - bn2_m[idx] * s2;
        float s3 = bn3_g[idx] * rsqrtf(bn3_v[idx] + EPSV);
        b2p[idx] = conv2_b[idx] * s3 + bn3_b[idx] - bn3_m[idx] * s3;
    }
    if (idx < 128) {
        float s1 = bn1_g[idx] * rsqrtf(bn1_v[idx] + EPSV);
        s1o[idx] = s1;
        t1o[idx] = bn1_b[idx] - bn1_m[idx] * s1;
    }
}

// ---------------------------------------------------------------------------
// Kernel B1: bilinear sample + maxpool -> xs bf16 swizzled [line][kg16][t8][8]
// ---------------------------------------------------------------------------
__global__ __launch_bounds__(256) void sample_kernel(
    const ushort* __restrict__ x, const float* __restrict__ lines,
    ushort* __restrict__ xsb)
{
    __shared__ int   sIdx[NPTS0][4];
    __shared__ float sWt[NPTS0][4];

    int n = blockIdx.x;
    int b = n / LL;
    int tid = threadIdx.x;

    if (tid < NPTS0) {
        int j = tid;
        float lam = (float)j * (1.0f / 31.0f);
        const float* lp = lines + (size_t)n * 4;
        float e0x = lp[0], e0y = lp[1], e1x = lp[2], e1y = lp[3];
        float px = e0x * lam + e1x * (1.f - lam) - 0.5f;
        float py = e0y * lam + e1y * (1.f - lam) - 0.5f;
        float px0 = fminf(fmaxf(floorf(px), 0.f), 255.f);
        float py0 = fminf(fmaxf(floorf(py), 0.f), 255.f);
        float px1 = fminf(px0 + 1.f, 255.f);
        float py1 = fminf(py0 + 1.f, 255.f);
        int ix0 = (int)px0, iy0 = (int)py0, ix1 = (int)px1, iy1 = (int)py1;
        sIdx[j][0] = ix0 * WW + iy0;
        sIdx[j][1] = ix1 * WW + iy0;
        sIdx[j][2] = ix0 * WW + iy1;
        sIdx[j][3] = ix1 * WW + iy1;
        sWt[j][0] = (px1 - px) * (py1 - py);
        sWt[j][1] = (px - px0) * (py1 - py);
        sWt[j][2] = (px1 - px) * (py - py0);
        sWt[j][3] = (px - px0) * (py - py0);
    }
    __syncthreads();

    int w = tid >> 6, lane = tid & 63;
    const uint* xb = (const uint*)(x + (size_t)b * HWP * CLOI);

    float m00 = -INFINITY, m10 = -INFINITY;
    float m01 = -INFINITY, m11 = -INFINITY;

#pragma unroll
    for (int jj = 0; jj < 8; jj++) {
        int j = w * 8 + jj;
        int i00 = sIdx[j][0], i10 = sIdx[j][1], i01 = sIdx[j][2], i11 = sIdx[j][3];
        float w00 = sWt[j][0], w10 = sWt[j][1], w01 = sWt[j][2], w11 = sWt[j][3];
        uint u00 = xb[(size_t)i00 * 64 + lane];
        uint u10 = xb[(size_t)i10 * 64 + lane];
        uint u01 = xb[(size_t)i01 * 64 + lane];
        uint u11 = xb[(size_t)i11 * 64 + lane];
        float v0 = bf2f((ushort)(u00 & 0xffff)) * w00 + bf2f((ushort)(u10 & 0xffff)) * w10
                 + bf2f((ushort)(u01 & 0xffff)) * w01 + bf2f((ushort)(u11 & 0xffff)) * w11;
        float v1 = bf2f((ushort)(u00 >> 16)) * w00 + bf2f((ushort)(u10 >> 16)) * w10
                 + bf2f((ushort)(u01 >> 16)) * w01 + bf2f((ushort)(u11 >> 16)) * w11;
        if (jj < 4) { m00 = fmaxf(m00, v0); m10 = fmaxf(m10, v1); }
        else        { m01 = fmaxf(m01, v0); m11 = fmaxf(m11, v1); }
    }

    // write: channels c0=2*lane, c0+1; el = kg*64 + t*8 + j
    ushort* basep = xsb + (size_t)n * 1024;
    int kg = lane >> 2;
    int j2 = (lane & 3) * 2;
    *(uint*)(basep + kg * 64 + (2 * w) * 8 + j2) = pack2(m00, m10);
    *(uint*)(basep + kg * 64 + (2 * w + 1) * 8 + j2) = pack2(m01, m11);
}

// ---------------------------------------------------------------------------
// Kernel B2: MFMA head. 8 lines/block, 4 waves, wave w owns cols w*16..w*16+15
// (col = l*8 + t). conv1/conv2(3 taps)/conv3 as 16x16x32 bf16 MFMA; residual +
// relu + fc2 per-lane fp32 with shuffle reduce.
// ---------------------------------------------------------------------------
__global__ __launch_bounds__(256) void head_kernel(
    const ushort* __restrict__ xsb,
    const ushort* __restrict__ w1s, const ushort* __restrict__ w2s,
    const ushort* __restrict__ w3s,
    const float* __restrict__ b1p, const float* __restrict__ b2p,
    const float* __restrict__ s1g, const float* __restrict__ t1g,
    const float* __restrict__ conv3_b,
    const float* __restrict__ fc2_w, const float* __restrict__ fc2_b,
    float* __restrict__ out)
{
    __shared__ ushort sXS[8192];   // [16kg][64col][8] raw xs bf16
    __shared__ ushort sH1[8192];   // h1; first 4096 reused as B3 (conv2 out)
    __shared__ ushort sB2[4096];   // [8kg][64col][8] conv1 out
    __shared__ float  sFC2[3072];  // fc2_w
    __shared__ float  sS1[128], sT1[128];
    __shared__ float  sB1[64], sB2b[64], sB3b[128];

    int tid = threadIdx.x;
    int wv = tid >> 6, lane = tid & 63;
    int q = lane >> 4, ln = lane & 15;
    int L0 = blockIdx.x * 8;
    int colg = wv * 16 + ln;

    // ---- params to LDS ----
    if (tid < 128) { sS1[tid] = s1g[tid]; sT1[tid] = t1g[tid]; sB3b[tid] = conv3_b[tid]; }
    if (tid < 64)  { sB1[tid] = b1p[tid]; sB2b[tid] = b2p[tid]; }
#pragma unroll
    for (int it = 0; it < 12; it++) sFC2[it * 256 + tid] = fc2_w[it * 256 + tid];
    __syncthreads();

    // ---- stage xs tile + compute h1 = relu(bn1(xs)) ----
#pragma unroll
    for (int it = 0; it < 4; it++) {
        int ch = it * 256 + tid;          // 0..1023
        int l = ch >> 7, wc = ch & 127;
        int kg = wc >> 3, tt = wc & 7;
        int col = l * 8 + tt;
        uint4 raw = *(const uint4*)(xsb + (size_t)(L0 + l) * 1024 + wc * 8);
        int off = (kg * 64 + col) * 8;
        *(uint4*)(&sXS[off]) = raw;
        uint rw[4] = { raw.x, raw.y, raw.z, raw.w };
        uint hw[4];
#pragma unroll
        for (int p = 0; p < 4; p++) {
            int c = kg * 8 + p * 2;
            float v0 = bf2f((ushort)(rw[p] & 0xffff));
            float v1 = bf2f((ushort)(rw[p] >> 16));
            float h0 = fmaxf(v0 * sS1[c] + sT1[c], 0.f);
            float h1v = fmaxf(v1 * sS1[c + 1] + sT1[c + 1], 0.f);
            hw[p] = pack2(h0, h1v);
        }
        uint4 hv; hv.x = hw[0]; hv.y = hw[1]; hv.z = hw[2]; hv.w = hw[3];
        *(uint4*)(&sH1[off]) = hv;
    }
    __syncthreads();

    const short8 bzero = { 0, 0, 0, 0, 0, 0, 0, 0 };
    const f32x4 fzero = { 0.f, 0.f, 0.f, 0.f };

    // ---- conv1: M=64, K=128 ----
    f32x4 acc1[4];
#pragma unroll
    for (int mt = 0; mt < 4; mt++) acc1[mt] = fzero;
#pragma unroll
    for (int ks = 0; ks < 4; ks++) {
        short8 b = *(short8*)(&sH1[((ks * 4 + q) * 64 + colg) * 8]);
#pragma unroll
        for (int mt = 0; mt < 4; mt++) {
            short8 a = *(const short8*)(w1s + ((ks * 4 + q) * 64 + mt * 16 + ln) * 8);
            acc1[mt] = __builtin_amdgcn_mfma_f32_16x16x32_bf16(a, b, acc1[mt], 0, 0, 0);
        }
    }
    // epilogue -> sB2
#pragma unroll
    for (int mt = 0; mt < 4; mt++) {
        int m0 = mt * 16 + q * 4;
        float v0 = fmaxf(acc1[mt][0] + sB1[m0 + 0], 0.f);
        float v1 = fmaxf(acc1[mt][1] + sB1[m0 + 1], 0.f);
        float v2 = fmaxf(acc1[mt][2] + sB1[m0 + 2], 0.f);
        float v3 = fmaxf(acc1[mt][3] + sB1[m0 + 3], 0.f);
        uint2 u; u.x = pack2(v0, v1); u.y = pack2(v2, v3);
        *(uint2*)(&sB2[((m0 >> 3) * 64 + colg) * 8 + (m0 & 7)]) = u;
    }
    __syncthreads();

    // ---- conv2: M=64, K=64 x 3 taps (shifted cols, zero at line edges) ----
    f32x4 acc2[4];
#pragma unroll
    for (int mt = 0; mt < 4; mt++) acc2[mt] = fzero;
    int tpos = colg & 7;
#pragma unroll
    for (int dt = 0; dt < 3; dt++) {
        int tsh = tpos + dt - 1;
        bool valid = ((unsigned)tsh < 8u);
        int colr = colg + dt - 1;
        colr = colr < 0 ? 0 : (colr > 63 ? 63 : colr);
#pragma unroll
        for (int ks = 0; ks < 2; ks++) {
            short8 b = *(short8*)(&sB2[((ks * 4 + q) * 64 + colr) * 8]);
            b = valid ? b : bzero;
#pragma unroll
            for (int mt = 0; mt < 4; mt++) {
                short8 a = *(const short8*)(w2s + dt * 4096 + ((ks * 4 + q) * 64 + mt * 16 + ln) * 8);
                acc2[mt] = __builtin_amdgcn_mfma_f32_16x16x32_bf16(a, b, acc2[mt], 0, 0, 0);
            }
        }
    }
    // epilogue -> B3 (reuse sH1)
#pragma unroll
    for (int mt = 0; mt < 4; mt++) {
        int m0 = mt * 16 + q * 4;
        float v0 = fmaxf(acc2[mt][0] + sB2b[m0 + 0], 0.f);
        float v1 = fmaxf(acc2[mt][1] + sB2b[m0 + 1], 0.f);
        float v2 = fmaxf(acc2[mt][2] + sB2b[m0 + 2], 0.f);
        float v3 = fmaxf(acc2[mt][3] + sB2b[m0 + 3], 0.f);
        uint2 u; u.x = pack2(v0, v1); u.y = pack2(v2, v3);
        *(uint2*)(&sH1[((m0 >> 3) * 64 + colg) * 8 + (m0 & 7)]) = u;
    }
    __syncthreads();

    // ---- conv3: M=128, K=64 ----
    f32x4 acc3[8];
#pragma unroll
    for (int mt = 0; mt < 8; mt++) acc3[mt] = fzero;
#pragma unroll
    for (int ks = 0; ks < 2; ks++) {
        short8 b = *(short8*)(&sH1[((ks * 4 + q) * 64 + colg) * 8]);
#pragma unroll
        for (int mt = 0; mt < 8; mt++) {
            short8 a = *(const short8*)(w3s + ((ks * 4 + q) * 128 + mt * 16 + ln) * 8);
            acc3[mt] = __builtin_amdgcn_mfma_f32_16x16x32_bf16(a, b, acc3[mt], 0, 0, 0);
        }
    }

    // ---- residual + relu + fc2 (per-lane fp32) ----
    float p0 = 0.f, p1 = 0.f, p2 = 0.f;
#pragma unroll
    for (int mt = 0; mt < 8; mt++) {
#pragma unroll
        for (int r = 0; r < 4; r++) {
            int m = mt * 16 + q * 4 + r;
            float xsv = bf2f(sXS[(m >> 3) * 512 + colg * 8 + (m & 7)]);
            float v = fmaxf(xsv + acc3[mt][r] + sB3b[m], 0.f);
            int fi = m * 8 + tpos;
            p0 += v * sFC2[fi];
            p1 += v * sFC2[1024 + fi];
            p2 += v * sFC2[2048 + fi];
        }
    }
    p0 += __shfl_xor(p0, 32); p1 += __shfl_xor(p1, 32); p2 += __shfl_xor(p2, 32);
    p0 += __shfl_xor(p0, 16); p1 += __shfl_xor(p1, 16); p2 += __shfl_xor(p2, 16);
    p0 += __shfl_xor(p0, 4);  p1 += __shfl_xor(p1, 4);  p2 += __shfl_xor(p2, 4);
    p0 += __shfl_xor(p0, 2);  p1 += __shfl_xor(p1, 2);  p2 += __shfl_xor(p2, 2);
    p0 += __shfl_xor(p0, 1);  p1 += __shfl_xor(p1, 1);  p2 += __shfl_xor(p2, 1);

    if (lane == 0 || lane == 8) {
        int line = L0 + wv * 2 + (lane >> 3);
        out[(size_t)line * 3 + 0] = p0 + fc2_b[0];
        out[(size_t)line * 3 + 1] = p1 + fc2_b[1];
        out[(size_t)line * 3 + 2] = p2 + fc2_b[2];
    }
}

extern "C" void kernel_launch(void* const* d_in, const int* in_sizes, int n_in,
                              void* d_out, int out_size, void* d_ws, size_t ws_size,
                              hipStream_t stream) {
    const float* feature = (const float*)d_in[0];
    const float* lines   = (const float*)d_in[1];
    const float* fc1_w   = (const float*)d_in[2];
    const float* fc1_b   = (const float*)d_in[3];
    const float* bn1_g   = (const float*)d_in[4];
    const float* bn1_b   = (const float*)d_in[5];
    const float* bn1_m   = (const float*)d_in[6];
    const float* bn1_v   = (const float*)d_in[7];
    const float* conv1_w = (const float*)d_in[8];
    const float* conv1_b = (const float*)d_in[9];
    const float* bn2_g   = (const float*)d_in[10];
    const float* bn2_b   = (const float*)d_in[11];
    const float* bn2_m   = (const float*)d_in[12];
    const float* bn2_v   = (const float*)d_in[13];
    const float* conv2_w = (const float*)d_in[14];
    const float* conv2_b = (const float*)d_in[15];
    const float* bn3_g   = (const float*)d_in[16];
    const float* bn3_b   = (const float*)d_in[17];
    const float* bn3_m   = (const float*)d_in[18];
    const float* bn3_v   = (const float*)d_in[19];
    const float* conv3_w = (const float*)d_in[20];
    const float* conv3_b = (const float*)d_in[21];
    const float* fc2_w   = (const float*)d_in[22];
    const float* fc2_b   = (const float*)d_in[23];
    float* out = (float*)d_out;

    char* ws = (char*)d_ws;
    ushort* x_bf = (ushort*)ws;
    ushort* xs_b = (ushort*)(ws + X_BYTES);
    ushort* w1s  = (ushort*)(ws + W1S_OFF);
    ushort* w2s  = (ushort*)(ws + W2S_OFF);
    ushort* w3s  = (ushort*)(ws + W3S_OFF);
    float*  b1p  = (float*)(ws + B1P_OFF);
    float*  b2p  = (float*)(ws + B2P_OFF);
    float*  s1g  = (float*)(ws + S1_OFF);
    float*  t1g  = (float*)(ws + T1_OFF);
    ushort* w0s  = (ushort*)(ws + W0S_OFF);

    prep_kernel<<<128, 256, 0, stream>>>(
        conv1_w, conv1_b, bn2_g, bn2_b, bn2_m, bn2_v,
        conv2_w, conv2_b, bn3_g, bn3_b, bn3_m, bn3_v,
        conv3_w, bn1_g, bn1_b, bn1_m, bn1_v, fc1_w,
        w1s, w2s, w3s, b1p, b2p, s1g, t1g, w0s);
    fc1_kernel<<<2048, 256, 0, stream>>>(feature, w0s, fc1_b, x_bf);
    sample_kernel<<<BB * LL, 256, 0, stream>>>(x_bf, lines, xs_b);
    head_kernel<<<BB * LL / 8, 256, 0, stream>>>(
        xs_b, w1s, w2s, w3s, b1p, b2p, s1g, t1g, conv3_b, fc2_w, fc2_b, out);
}